// Round 22
// baseline (270.525 us; speedup 1.0000x reference)
//
#include <hip/hip_runtime.h>

typedef __bf16 bf16_t;
typedef __bf16 bf16x8 __attribute__((ext_vector_type(8)));
typedef float f32x4 __attribute__((ext_vector_type(4)));
typedef float f32x16 __attribute__((ext_vector_type(16)));
typedef unsigned short u16;
typedef unsigned int u32;

#define NTOK 1025
#define MTOT 8200
#define MPAD 8448
#define CDIM 768

// async inline-asm load for the GEMM pipeline (forces dest regs live; rule #18)
#define GLOAD(dst, p) \
  asm volatile("global_load_dwordx4 %0, %1, off" : "=&v"(dst) : "v"((const void*)(p)))

__device__ __forceinline__ u16 f2bf(float f) {
  union { float f; unsigned u; } v; v.f = f;
  unsigned r = v.u + 0x7fffu + ((v.u >> 16) & 1u);
  return (u16)(r >> 16);
}
__device__ __forceinline__ float bf2f(u16 h) {
  union { unsigned u; float f; } v; v.u = ((unsigned)h) << 16; return v.f;
}
__device__ __forceinline__ u32 cvtpk(float lo, float hi) {
  u32 r; asm("v_cvt_pk_bf16_f32 %0, %1, %2" : "=v"(r) : "v"(lo), "v"(hi)); return r;
}

// ---------------- K0a: x fp32 -> xf fragment layout [mt][kt 24][lane 64][8] ----------------
__global__ __launch_bounds__(256) void conv_xf(const float4* __restrict__ x4,
                                               u16* __restrict__ xf) {
  __shared__ u16 tile[16][776];
  int mt = blockIdx.x;
  int t = threadIdx.x;
#pragma unroll
  for (int it = 0; it < 12; ++it) {
    int id = it * 256 + t;
    int r = id / 192, c4 = id % 192;
    int m = mt * 16 + r;
    if (m < MTOT) {
      float4 f = x4[(size_t)m * 192 + c4];
      ushort4 o; o.x = f2bf(f.x); o.y = f2bf(f.y); o.z = f2bf(f.z); o.w = f2bf(f.w);
      *(ushort4*)&tile[r][c4 * 4] = o;
    }
  }
  __syncthreads();
#pragma unroll
  for (int it = 0; it < 6; ++it) {
    int cid = it * 256 + t;
    int kt = cid >> 6, lane = cid & 63;
    uint4 w = *(const uint4*)&tile[lane & 15][kt * 32 + (lane >> 4) * 8];
    *(uint4*)&xf[(((size_t)mt * 24 + kt) * 64 + lane) * 8] = w;
  }
}

// ---------------- K0b: weights [768][N] fp32 -> wf fragment layout [nt][kt][lane][8] ----------------
__global__ __launch_bounds__(64) void transp_wf(const float* __restrict__ in, int N,
                                                u16* __restrict__ wf) {
  __shared__ u16 lds[16][32];
  int n0 = blockIdx.x * 16, k0 = blockIdx.y * 32;
  int t = threadIdx.x;
#pragma unroll
  for (int it = 0; it < 8; ++it) {
    int e = it * 64 + t;
    int kk = e >> 4, nn = e & 15;
    lds[nn][kk] = f2bf(in[(size_t)(k0 + kk) * N + n0 + nn]);
  }
  __syncthreads();
  uint4 w = *(const uint4*)&lds[t & 15][(t >> 4) * 8];
  *(uint4*)&wf[((((size_t)(n0 >> 4)) * 24 + (k0 >> 5)) * 64 + t) * 8] = w;
}

// ---------------- fragment-direct K-loop, asm-enforced 3-deep pipeline (r13/r14-proven) ----------------
template <bool TRANS>
__device__ __forceinline__ void fdloop(const u16* __restrict__ afr, const u16* __restrict__ bfr,
                                       int m0, int n0, int lane, int wr, int wc,
                                       f32x4 (*acc)[4]) {
  const u16* ab = afr + ((size_t)((m0 >> 4) + wr * 4) * 1536 + lane) * 8;
  const u16* bb = bfr + ((size_t)((n0 >> 4) + wc * 4) * 1536 + lane) * 8;
  bf16x8 S[3][8];
  auto LOADA = [&](int s, int kt) {
#pragma unroll
    for (int i = 0; i < 4; ++i)
      GLOAD(S[s][i], ab + (size_t)i * 12288 + (size_t)kt * 512);
#pragma unroll
    for (int j = 0; j < 4; ++j)
      GLOAD(S[s][4 + j], bb + (size_t)j * 12288 + (size_t)kt * 512);
  };
  auto COMP = [&](bf16x8 (&Sc)[8]) {
    __builtin_amdgcn_s_setprio(1);
#pragma unroll
    for (int x = 0; x < 4; ++x)
#pragma unroll
      for (int y = 0; y < 4; ++y)
        acc[x][y] = TRANS
            ? __builtin_amdgcn_mfma_f32_16x16x32_bf16(Sc[4 + x], Sc[y], acc[x][y], 0, 0, 0)
            : __builtin_amdgcn_mfma_f32_16x16x32_bf16(Sc[x], Sc[4 + y], acc[x][y], 0, 0, 0);
    __builtin_amdgcn_s_setprio(0);
  };
  LOADA(0, 0);
  LOADA(1, 1);
#pragma unroll
  for (int kt = 0; kt < 24; ++kt) {
    if (kt < 22) {
      LOADA((kt + 2) % 3, kt + 2);
      asm volatile("s_waitcnt vmcnt(16)");
    } else if (kt == 22) {
      asm volatile("s_waitcnt vmcnt(8)");
    } else {
      asm volatile("s_waitcnt vmcnt(0)");
    }
    __builtin_amdgcn_sched_barrier(0);
    COMP(S[kt % 3]);
  }
}

// ---------------- K1: merged QKV GEMM (1170 blocks; bx<12 -> q/k path, else v path) ----------------
__global__ __launch_bounds__(256, 3) void qkv_gemm_all(
    const u16* __restrict__ xf, const u16* __restrict__ wf,
    const float* __restrict__ qbias, const float* __restrict__ vbias,
    const float* __restrict__ rope,
    u16* __restrict__ q, u16* __restrict__ kfr, u16* __restrict__ vfr) {
  const int NB = 18;
  int tau0 = blockIdx.x;
  int xcd = tau0 & 7, pos = tau0 >> 3;
  int tau = (xcd < 2) ? xcd * 147 + pos : 294 + (xcd - 2) * 146 + pos;  // 1170 = 8*146+2
  int bx = tau % NB, by = tau / NB;
  int m0 = by * 128;
  int t = threadIdx.x;
  int lane = t & 63, wave = t >> 6;
  int ln = lane & 15, hi = lane >> 4;
  int wr = wave >> 1, wc = wave & 1;

  if (bx < 12) {
    int n0 = bx * 128;
    f32x4 acc[4][4] = {};
    fdloop<true>(xf, wf, m0, n0, lane, wr, wc, acc);

    const float scale = 0.125f * 1.4426950408889634f;
#pragma unroll
    for (int ii = 0; ii < 4; ++ii) {
      int m = m0 + wr * 64 + ii * 16 + ln;
      if (m < MTOT) {
        int b = m / NTOK;
        int n = m - b * NTOK;
        const float* rp = rope + (size_t)(n - 1) * 128;
#pragma unroll
        for (int jj = 0; jj < 4; ++jj) {
          int c4 = n0 + wc * 64 + jj * 16 + hi * 4;
          int part = (c4 >= CDIM) ? 1 : 0;
          int cc = c4 - part * CDIM;
          int h = cc >> 6, d4 = cc & 63;
          float v0 = acc[jj][ii][0], v1 = acc[jj][ii][1];
          float v2 = acc[jj][ii][2], v3 = acc[jj][ii][3];
          if (part == 0) {
            float4 qb = *(const float4*)(qbias + cc);
            v0 += qb.x; v1 += qb.y; v2 += qb.z; v3 += qb.w;
          }
          float o0, o1, o2, o3;
          if (n > 0) {
            float4 sn = *(const float4*)(rp + d4);
            float4 cs = *(const float4*)(rp + 64 + d4);
            o0 = v0 * cs.x - v1 * sn.x;
            o1 = v1 * cs.y + v0 * sn.y;
            o2 = v2 * cs.z - v3 * sn.z;
            o3 = v3 * cs.w + v2 * sn.w;
          } else { o0 = v0; o1 = v1; o2 = v2; o3 = v3; }
          uint2 w;
          if (part == 0) {
            w.x = cvtpk(o0 * scale, o1 * scale); w.y = cvtpk(o2 * scale, o3 * scale);
            *(uint2*)(q + ((size_t)(h * MPAD + m)) * 64 + d4) = w;
          } else {
            w.x = cvtpk(o0, o1); w.y = cvtpk(o2, o3);
            int kt2 = n >> 5, lqn = n & 31;
            int sF = d4 >> 4, h2d = (d4 >> 3) & 1, j0 = d4 & 7;
            u16* dst = kfr + ((((size_t)(h * 8 + b) * 34 + kt2) * 4 + sF) * 64
                              + h2d * 32 + lqn) * 8 + j0;
            *(uint2*)dst = w;
          }
        }
      }
    }
  } else {
    int n0 = 1536 + (bx - 12) * 128;
    f32x4 acc[4][4] = {};
    fdloop<false>(xf, wf, m0, n0, lane, wr, wc, acc);

#pragma unroll
    for (int i = 0; i < 4; ++i) {
      int mrow = m0 + wr * 64 + i * 16 + hi * 4;
#pragma unroll
      for (int j = 0; j < 4; ++j) {
        int cv = n0 - 1536 + wc * 64 + j * 16 + ln;
        int h = cv >> 6, d = cv & 63;
        int hf = d >> 5, lqd = d & 31;
        float vb = vbias[cv];
#pragma unroll
        for (int r = 0; r < 4; ++r) {
          int mr = mrow + r;
          if (mr < MTOT) {
            int b = mr / NTOK;
            int n = mr - b * NTOK;
            size_t idx = ((((size_t)(h * 8 + b) * 17 + (n >> 6)) * 4 + ((n >> 4) & 3)) * 2 + hf) * 512
                       + (size_t)((((n >> 3) & 1) * 32 + lqd) * 8 + (n & 7));
            vfr[idx] = f2bf(acc[i][j][r] + vb);
          }
        }
      }
    }
  }
}

// ---------------- flash iteration body: K AND V ping-pong prefetch (r17-measured-best) ----------------
template <bool PF, bool MASK>
__device__ __forceinline__ void flash_iter(
    bf16x8 (&kf)[8], bf16x8 (&kn)[8],
    bf16x8 (&vf)[8], bf16x8 (&vn)[8],
    int pftile, int it,
    const u16* kfb, const u16* vfb, int h2,
    const bf16x8 (&qf)[4], f32x16 (&acc)[2], float& l) {
  if (PF) {
    const u16* kp2 = kfb + (size_t)pftile * 4096;
#pragma unroll
    for (int c = 0; c < 2; ++c)
#pragma unroll
      for (int s = 0; s < 4; ++s)
        kn[c * 4 + s] = *(const bf16x8*)(kp2 + c * 2048 + s * 512);
    const u16* vp2 = vfb + (size_t)pftile * 4096;
#pragma unroll
    for (int hf = 0; hf < 2; ++hf)
#pragma unroll
      for (int s = 0; s < 4; ++s)
        vn[hf * 4 + s] = *(const bf16x8*)(vp2 + (s * 2 + hf) * 512);
  }
  f32x16 sc[2] = {};
  __builtin_amdgcn_s_setprio(1);
#pragma unroll
  for (int c = 0; c < 2; ++c)
#pragma unroll
    for (int s = 0; s < 4; ++s)
      sc[c] = __builtin_amdgcn_mfma_f32_32x32x16_bf16(kf[c * 4 + s], qf[s], sc[c], 0, 0, 0);
  __builtin_amdgcn_s_setprio(0);
#pragma unroll
  for (int c = 0; c < 2; ++c)
#pragma unroll
    for (int r = 0; r < 16; ++r)
      sc[c][r] = __builtin_amdgcn_exp2f(sc[c][r]);
  if (MASK) {
#pragma unroll
    for (int c = 0; c < 2; ++c)
#pragma unroll
      for (int r = 0; r < 16; ++r) {
        int kk = it * 64 + c * 32 + (r & 3) + 8 * (r >> 2) + 4 * h2;
        if (kk >= NTOK) sc[c][r] = 0.f;
      }
  }
  float rs = 0.f;
#pragma unroll
  for (int c = 0; c < 2; ++c)
#pragma unroll
    for (int r = 0; r < 16; ++r) rs += sc[c][r];
  l += rs;
  bf16x8 frag[4];
#pragma unroll
  for (int c = 0; c < 2; ++c) {
    u32 k0 = cvtpk(sc[c][0], sc[c][1]),   k1 = cvtpk(sc[c][2], sc[c][3]);
    u32 k2 = cvtpk(sc[c][4], sc[c][5]),   k3 = cvtpk(sc[c][6], sc[c][7]);
    u32 k4 = cvtpk(sc[c][8], sc[c][9]),   k5 = cvtpk(sc[c][10], sc[c][11]);
    u32 k6 = cvtpk(sc[c][12], sc[c][13]), k7 = cvtpk(sc[c][14], sc[c][15]);
    asm("v_permlane32_swap_b32 %0, %1" : "+v"(k0), "+v"(k2));
    asm("v_permlane32_swap_b32 %0, %1" : "+v"(k1), "+v"(k3));
    asm("v_permlane32_swap_b32 %0, %1" : "+v"(k4), "+v"(k6));
    asm("v_permlane32_swap_b32 %0, %1" : "+v"(k5), "+v"(k7));
    union { u32 u[4]; bf16x8 v; } u0, u1;
    u0.u[0] = k0; u0.u[1] = k1; u0.u[2] = k2; u0.u[3] = k3;
    u1.u[0] = k4; u1.u[1] = k5; u1.u[2] = k6; u1.u[3] = k7;
    frag[c * 2] = u0.v; frag[c * 2 + 1] = u1.v;
  }
  __builtin_amdgcn_s_setprio(1);
#pragma unroll
  for (int hf = 0; hf < 2; ++hf)
#pragma unroll
    for (int s = 0; s < 4; ++s)
      acc[hf] = __builtin_amdgcn_mfma_f32_32x32x16_bf16(vf[hf * 4 + s], frag[s], acc[hf], 0, 0, 0);
  __builtin_amdgcn_s_setprio(0);
}

// ---------------- K3: flash attention — barrier-free, K+V register ping-pong ----------------
__global__ __launch_bounds__(256, 3) void flash_attn(
    const u16* __restrict__ q, const u16* __restrict__ kfr,
    const u16* __restrict__ vfr, u16* __restrict__ y) {
  int f = blockIdx.x;                 // 864 = 8 XCD-chunks * 108
  int xcd = f & 7, idx = f >> 3;
  int bh = xcd * 12 + idx / 9;
  int qt = idx - (idx / 9) * 9;
  int b = bh / 12, h = bh - b * 12;
  int t = threadIdx.x, lane = t & 63, w = t >> 6;
  int lq = lane & 31, h2 = lane >> 5;
  int q0 = qt * 128 + w * 32;
  if (q0 >= NTOK) return;
  int qrow = q0 + lq; if (qrow > NTOK - 1) qrow = NTOK - 1;

  const u16* qp = q + ((size_t)(h * MPAD) + (size_t)b * NTOK + qrow) * 64;
  bf16x8 qf[4];
#pragma unroll
  for (int s = 0; s < 4; ++s)
    qf[s] = *(const bf16x8*)&qp[s * 16 + h2 * 8];

  const u16* kfb = kfr + (size_t)(h * 8 + b) * 34 * 2048 + lane * 8;
  const u16* vfb = vfr + (size_t)(h * 8 + b) * 17 * 4096 + lane * 8;

  f32x16 acc[2] = {};
  float l = 0.f;

  bf16x8 ka[8], kb2[8], va[8], vb[8];
#pragma unroll
  for (int c = 0; c < 2; ++c)
#pragma unroll
    for (int s = 0; s < 4; ++s)
      ka[c * 4 + s] = *(const bf16x8*)(kfb + c * 2048 + s * 512);
#pragma unroll
  for (int hf = 0; hf < 2; ++hf)
#pragma unroll
    for (int s = 0; s < 4; ++s)
      va[hf * 4 + s] = *(const bf16x8*)(vfb + (s * 2 + hf) * 512);

#pragma unroll 1
  for (int i2 = 0; i2 < 8; ++i2) {
    flash_iter<true, false>(ka, kb2, va, vb, 2 * i2 + 1, 2 * i2, kfb, vfb, h2, qf, acc, l);
    flash_iter<true, false>(kb2, ka, vb, va, 2 * i2 + 2, 2 * i2 + 1, kfb, vfb, h2, qf, acc, l);
  }
  flash_iter<false, true>(ka, kb2, va, vb, 0, 16, kfb, vfb, h2, qf, acc, l);

  int row = q0 + lq;
  if (row < NTOK) {
    float lt = l + __shfl_xor(l, 32, 64);
    float inv = 1.f / lt;
    u16* yr = y + ((size_t)(b * NTOK + row)) * CDIM + h * 64;
#pragma unroll
    for (int hf = 0; hf < 2; ++hf)
#pragma unroll
      for (int g = 0; g < 4; ++g) {
        int d0 = hf * 32 + 8 * g + 4 * h2;
        ushort4 o;
        o.x = f2bf(acc[hf][g * 4 + 0] * inv);
        o.y = f2bf(acc[hf][g * 4 + 1] * inv);
        o.z = f2bf(acc[hf][g * 4 + 2] * inv);
        o.w = f2bf(acc[hf][g * 4 + 3] * inv);
        *(ushort4*)&yr[d0] = o;
      }
  }
}

// ---------------- K4: LayerNorm (bf16 in) -> yf fragment layout ----------------
__global__ __launch_bounds__(256) void lnorm(const u16* __restrict__ y,
                                             const float* __restrict__ gamma,
                                             const float* __restrict__ beta,
                                             u16* __restrict__ yf) {
  int row = blockIdx.x;
  const u16* yr = y + (size_t)row * CDIM;
  int t = threadIdx.x;
  float v[3];
  float s = 0.f, s2 = 0.f;
#pragma unroll
  for (int i = 0; i < 3; ++i) {
    v[i] = bf2f(yr[t + 256 * i]);
    s += v[i]; s2 += v[i] * v[i];
  }
#pragma unroll
  for (int msk = 1; msk < 64; msk <<= 1) {
    s  += __shfl_xor(s, msk, 64);
    s2 += __shfl_xor(s2, msk, 64);
  }
  __shared__ float ws[8];
  int w = t >> 6, lane = t & 63;
  if (lane == 0) { ws[w] = s; ws[4 + w] = s2; }
  __syncthreads();
  s = ws[0] + ws[1] + ws[2] + ws[3];
  s2 = ws[4] + ws[5] + ws[6] + ws[7];
  float mu = s * (1.f / 768.f);
  float var = s2 * (1.f / 768.f) - mu * mu;
  float rstd = rsqrtf(var + 1e-6f);
  if (t < 96) {
    union { uint4 u4; u16 u[8]; } iv, ov;
    iv.u4 = *(const uint4*)&yr[t * 8];
    const float* gp = gamma + t * 8;
    const float* bp = beta + t * 8;
#pragma unroll
    for (int j = 0; j < 8; ++j)
      ov.u[j] = f2bf((bf2f(iv.u[j]) - mu) * rstd * gp[j] + bp[j]);
    int kt = t >> 2, ln2 = (row & 15) + 16 * (t & 3), mt = row >> 4;
    *(uint4*)&yf[(((size_t)mt * 24 + kt) * 64 + ln2) * 8] = ov.u4;
  }
}

// ---------------- K5: proj GEMM (fragment-direct, transposed frags) + bias -> fp32 ----------------
__global__ __launch_bounds__(256, 3) void proj_gemm(
    const u16* __restrict__ yf, const u16* __restrict__ wf,
    const float* __restrict__ bias, float* __restrict__ out) {
  const int NB = 6;
  int tau0 = blockIdx.x;
  int xcd = tau0 & 7, pos = tau0 >> 3;
  int tau = (xcd < 6) ? xcd * 49 + pos : 294 + (xcd - 6) * 48 + pos;
  int bx = tau % NB, by = tau / NB;
  int m0 = by * 128, n0 = bx * 128;
  int t = threadIdx.x;
  int lane = t & 63, wave = t >> 6;
  int ln = lane & 15, hi = lane >> 4;
  int wr = wave >> 1, wc = wave & 1;

  f32x4 acc[4][4] = {};
  fdloop<true>(yf, wf, m0, n0, lane, wr, wc, acc);

#pragma unroll
  for (int ii = 0; ii < 4; ++ii) {
    int m = m0 + wr * 64 + ii * 16 + ln;
    if (m < MTOT) {
      float* dr = out + (size_t)m * CDIM;
#pragma unroll
      for (int jj = 0; jj < 4; ++jj) {
        int c4 = n0 + wc * 64 + jj * 16 + hi * 4;
        float4 bv = *(const float4*)(bias + c4);
        float4 o;
        o.x = acc[jj][ii][0] + bv.x;
        o.y = acc[jj][ii][1] + bv.y;
        o.z = acc[jj][ii][2] + bv.z;
        o.w = acc[jj][ii][3] + bv.w;
        *(float4*)(dr + c4) = o;
      }
    }
  }
}

extern "C" void kernel_launch(void* const* d_in, const int* in_sizes, int n_in,
                              void* d_out, int out_size, void* d_ws, size_t ws_size,
                              hipStream_t stream) {
  const float* x      = (const float*)d_in[0];
  const float* rope   = (const float*)d_in[1];
  const float* w_qkv  = (const float*)d_in[2];
  const float* q_bias = (const float*)d_in[3];
  const float* v_bias = (const float*)d_in[4];
  const float* gamma  = (const float*)d_in[5];
  const float* beta   = (const float*)d_in[6];
  const float* w_proj = (const float*)d_in[7];
  const float* b_proj = (const float*)d_in[8];
  float* out = (float*)d_out;

  // Workspace (57.4 MB):
  //  A [0, 12.98M):        xf [528][24][64][8]  -> ybf [8200][768]
  //  B [12.98M, 16.52M):   wfq [144][24][64][8]
  //  C [16.52M, 17.69M):   wfp [48][24][64][8]
  //  D [17.69M, 30.67M):   qbuf [12][8448][64]  -> yf (lnorm frag out)
  //  E [30.67M, 44.04M):   kfr [96][34][4][64][8]
  //  F [44.04M, 57.41M):   vfr [96][17][4][2][64][8]
  char* ws = (char*)d_ws;
  u16* xf   = (u16*)(ws);
  u16* ybf  = (u16*)(ws);
  u16* wfq  = (u16*)(ws + 12976128);
  u16* wfp  = (u16*)(ws + 16515072);
  u16* qbuf = (u16*)(ws + 17694720);
  u16* yf   = (u16*)(ws + 17694720);
  u16* kfr  = (u16*)(ws + 30670848);
  u16* vfr  = (u16*)(ws + 44040192);

  conv_xf<<<dim3(513), 256, 0, stream>>>((const float4*)x, xf);
  transp_wf<<<dim3(144, 24), 64, 0, stream>>>(w_qkv, 2304, wfq);
  transp_wf<<<dim3(48, 24), 64, 0, stream>>>(w_proj, 768, wfp);

  qkv_gemm_all<<<dim3(1170), 256, 0, stream>>>(xf, wfq, q_bias, v_bias, rope,
                                               qbuf, kfr, vfr);
  flash_attn<<<dim3(864), 256, 0, stream>>>(qbuf, kfr, vfr, ybf);
  lnorm<<<8200, 256, 0, stream>>>(ybf, gamma, beta, yf);
  proj_gemm<<<dim3(390), 256, 0, stream>>>(yf, wfp, b_proj, out);
}

// Round 23
// 154.888 us; speedup vs baseline: 1.7466x; 1.7466x over previous
//
#include <hip/hip_runtime.h>

typedef __bf16 bf16_t;
typedef __bf16 bf16x8 __attribute__((ext_vector_type(8)));
typedef float f32x4 __attribute__((ext_vector_type(4)));
typedef float f32x16 __attribute__((ext_vector_type(16)));
typedef unsigned short u16;
typedef unsigned int u32;

#define NTOK 1025
#define MTOT 8200
#define MPAD 8448
#define CDIM 768

// async inline-asm load for the GEMM pipeline (forces dest regs live; rule #18)
#define GLOAD(dst, p) \
  asm volatile("global_load_dwordx4 %0, %1, off" : "=&v"(dst) : "v"((const void*)(p)))

__device__ __forceinline__ u16 f2bf(float f) {
  union { float f; unsigned u; } v; v.f = f;
  unsigned r = v.u + 0x7fffu + ((v.u >> 16) & 1u);
  return (u16)(r >> 16);
}
__device__ __forceinline__ float bf2f(u16 h) {
  union { unsigned u; float f; } v; v.u = ((unsigned)h) << 16; return v.f;
}
__device__ __forceinline__ u32 cvtpk(float lo, float hi) {
  u32 r; asm("v_cvt_pk_bf16_f32 %0, %1, %2" : "=v"(r) : "v"(lo), "v"(hi)); return r;
}

// ---------------- K0a: x fp32 -> xf fragment layout [mt][kt 24][lane 64][8] ----------------
__global__ __launch_bounds__(256) void conv_xf(const float4* __restrict__ x4,
                                               u16* __restrict__ xf) {
  __shared__ u16 tile[16][776];
  int mt = blockIdx.x;
  int t = threadIdx.x;
#pragma unroll
  for (int it = 0; it < 12; ++it) {
    int id = it * 256 + t;
    int r = id / 192, c4 = id % 192;
    int m = mt * 16 + r;
    if (m < MTOT) {
      float4 f = x4[(size_t)m * 192 + c4];
      ushort4 o; o.x = f2bf(f.x); o.y = f2bf(f.y); o.z = f2bf(f.z); o.w = f2bf(f.w);
      *(ushort4*)&tile[r][c4 * 4] = o;
    }
  }
  __syncthreads();
#pragma unroll
  for (int it = 0; it < 6; ++it) {
    int cid = it * 256 + t;
    int kt = cid >> 6, lane = cid & 63;
    uint4 w = *(const uint4*)&tile[lane & 15][kt * 32 + (lane >> 4) * 8];
    *(uint4*)&xf[(((size_t)mt * 24 + kt) * 64 + lane) * 8] = w;
  }
}

// ---------------- K0b: weights [768][N] fp32 -> wf fragment layout [nt][kt][lane][8] ----------------
__global__ __launch_bounds__(64) void transp_wf(const float* __restrict__ in, int N,
                                                u16* __restrict__ wf) {
  __shared__ u16 lds[16][32];
  int n0 = blockIdx.x * 16, k0 = blockIdx.y * 32;
  int t = threadIdx.x;
#pragma unroll
  for (int it = 0; it < 8; ++it) {
    int e = it * 64 + t;
    int kk = e >> 4, nn = e & 15;
    lds[nn][kk] = f2bf(in[(size_t)(k0 + kk) * N + n0 + nn]);
  }
  __syncthreads();
  uint4 w = *(const uint4*)&lds[t & 15][(t >> 4) * 8];
  *(uint4*)&wf[((((size_t)(n0 >> 4)) * 24 + (k0 >> 5)) * 64 + t) * 8] = w;
}

// ---------------- fragment-direct K-loop, asm-enforced 3-deep pipeline (r13/r14-proven) ----------------
template <bool TRANS>
__device__ __forceinline__ void fdloop(const u16* __restrict__ afr, const u16* __restrict__ bfr,
                                       int m0, int n0, int lane, int wr, int wc,
                                       f32x4 (*acc)[4]) {
  const u16* ab = afr + ((size_t)((m0 >> 4) + wr * 4) * 1536 + lane) * 8;
  const u16* bb = bfr + ((size_t)((n0 >> 4) + wc * 4) * 1536 + lane) * 8;
  bf16x8 S[3][8];
  auto LOADA = [&](int s, int kt) {
#pragma unroll
    for (int i = 0; i < 4; ++i)
      GLOAD(S[s][i], ab + (size_t)i * 12288 + (size_t)kt * 512);
#pragma unroll
    for (int j = 0; j < 4; ++j)
      GLOAD(S[s][4 + j], bb + (size_t)j * 12288 + (size_t)kt * 512);
  };
  auto COMP = [&](bf16x8 (&Sc)[8]) {
    __builtin_amdgcn_s_setprio(1);
#pragma unroll
    for (int x = 0; x < 4; ++x)
#pragma unroll
      for (int y = 0; y < 4; ++y)
        acc[x][y] = TRANS
            ? __builtin_amdgcn_mfma_f32_16x16x32_bf16(Sc[4 + x], Sc[y], acc[x][y], 0, 0, 0)
            : __builtin_amdgcn_mfma_f32_16x16x32_bf16(Sc[x], Sc[4 + y], acc[x][y], 0, 0, 0);
    __builtin_amdgcn_s_setprio(0);
  };
  LOADA(0, 0);
  LOADA(1, 1);
#pragma unroll
  for (int kt = 0; kt < 24; ++kt) {
    if (kt < 22) {
      LOADA((kt + 2) % 3, kt + 2);
      asm volatile("s_waitcnt vmcnt(16)");
    } else if (kt == 22) {
      asm volatile("s_waitcnt vmcnt(8)");
    } else {
      asm volatile("s_waitcnt vmcnt(0)");
    }
    __builtin_amdgcn_sched_barrier(0);
    COMP(S[kt % 3]);
  }
}

// ---------------- K1: merged QKV GEMM (1170 blocks; bx<12 -> q/k path, else v path) ----------------
__global__ __launch_bounds__(256, 3) void qkv_gemm_all(
    const u16* __restrict__ xf, const u16* __restrict__ wf,
    const float* __restrict__ qbias, const float* __restrict__ vbias,
    const float* __restrict__ rope,
    u16* __restrict__ q, u16* __restrict__ kfr, u16* __restrict__ vfr) {
  const int NB = 18;
  int tau0 = blockIdx.x;
  int xcd = tau0 & 7, pos = tau0 >> 3;
  int tau = (xcd < 2) ? xcd * 147 + pos : 294 + (xcd - 2) * 146 + pos;  // 1170 = 8*146+2
  int bx = tau % NB, by = tau / NB;
  int m0 = by * 128;
  int t = threadIdx.x;
  int lane = t & 63, wave = t >> 6;
  int ln = lane & 15, hi = lane >> 4;
  int wr = wave >> 1, wc = wave & 1;

  if (bx < 12) {
    int n0 = bx * 128;
    f32x4 acc[4][4] = {};
    fdloop<true>(xf, wf, m0, n0, lane, wr, wc, acc);

    const float scale = 0.125f * 1.4426950408889634f;
#pragma unroll
    for (int ii = 0; ii < 4; ++ii) {
      int m = m0 + wr * 64 + ii * 16 + ln;
      if (m < MTOT) {
        int b = m / NTOK;
        int n = m - b * NTOK;
        const float* rp = rope + (size_t)(n - 1) * 128;
#pragma unroll
        for (int jj = 0; jj < 4; ++jj) {
          int c4 = n0 + wc * 64 + jj * 16 + hi * 4;
          int part = (c4 >= CDIM) ? 1 : 0;
          int cc = c4 - part * CDIM;
          int h = cc >> 6, d4 = cc & 63;
          float v0 = acc[jj][ii][0], v1 = acc[jj][ii][1];
          float v2 = acc[jj][ii][2], v3 = acc[jj][ii][3];
          if (part == 0) {
            float4 qb = *(const float4*)(qbias + cc);
            v0 += qb.x; v1 += qb.y; v2 += qb.z; v3 += qb.w;
          }
          float o0, o1, o2, o3;
          if (n > 0) {
            float4 sn = *(const float4*)(rp + d4);
            float4 cs = *(const float4*)(rp + 64 + d4);
            o0 = v0 * cs.x - v1 * sn.x;
            o1 = v1 * cs.y + v0 * sn.y;
            o2 = v2 * cs.z - v3 * sn.z;
            o3 = v3 * cs.w + v2 * sn.w;
          } else { o0 = v0; o1 = v1; o2 = v2; o3 = v3; }
          uint2 w;
          if (part == 0) {
            w.x = cvtpk(o0 * scale, o1 * scale); w.y = cvtpk(o2 * scale, o3 * scale);
            *(uint2*)(q + ((size_t)(h * MPAD + m)) * 64 + d4) = w;
          } else {
            w.x = cvtpk(o0, o1); w.y = cvtpk(o2, o3);
            int kt2 = n >> 5, lqn = n & 31;
            int sF = d4 >> 4, h2d = (d4 >> 3) & 1, j0 = d4 & 7;
            u16* dst = kfr + ((((size_t)(h * 8 + b) * 34 + kt2) * 4 + sF) * 64
                              + h2d * 32 + lqn) * 8 + j0;
            *(uint2*)dst = w;
          }
        }
      }
    }
  } else {
    int n0 = 1536 + (bx - 12) * 128;
    f32x4 acc[4][4] = {};
    fdloop<false>(xf, wf, m0, n0, lane, wr, wc, acc);

#pragma unroll
    for (int i = 0; i < 4; ++i) {
      int mrow = m0 + wr * 64 + i * 16 + hi * 4;
#pragma unroll
      for (int j = 0; j < 4; ++j) {
        int cv = n0 - 1536 + wc * 64 + j * 16 + ln;
        int h = cv >> 6, d = cv & 63;
        int hf = d >> 5, lqd = d & 31;
        float vb = vbias[cv];
#pragma unroll
        for (int r = 0; r < 4; ++r) {
          int mr = mrow + r;
          if (mr < MTOT) {
            int b = mr / NTOK;
            int n = mr - b * NTOK;
            size_t idx = ((((size_t)(h * 8 + b) * 17 + (n >> 6)) * 4 + ((n >> 4) & 3)) * 2 + hf) * 512
                       + (size_t)((((n >> 3) & 1) * 32 + lqd) * 8 + (n & 7));
            vfr[idx] = f2bf(acc[i][j][r] + vb);
          }
        }
      }
    }
  }
}

// ---------------- flash iteration body: K AND V ping-pong prefetch (r17-measured-best) ----------------
template <bool PF, bool MASK>
__device__ __forceinline__ void flash_iter(
    bf16x8 (&kf)[8], bf16x8 (&kn)[8],
    bf16x8 (&vf)[8], bf16x8 (&vn)[8],
    int pftile, int it,
    const u16* kfb, const u16* vfb, int h2,
    const bf16x8 (&qf)[4], f32x16 (&acc)[2], float& l) {
  if (PF) {
    const u16* kp2 = kfb + (size_t)pftile * 4096;
#pragma unroll
    for (int c = 0; c < 2; ++c)
#pragma unroll
      for (int s = 0; s < 4; ++s)
        kn[c * 4 + s] = *(const bf16x8*)(kp2 + c * 2048 + s * 512);
    const u16* vp2 = vfb + (size_t)pftile * 4096;
#pragma unroll
    for (int hf = 0; hf < 2; ++hf)
#pragma unroll
      for (int s = 0; s < 4; ++s)
        vn[hf * 4 + s] = *(const bf16x8*)(vp2 + (s * 2 + hf) * 512);
  }
  f32x16 sc[2] = {};
  __builtin_amdgcn_s_setprio(1);
#pragma unroll
  for (int c = 0; c < 2; ++c)
#pragma unroll
    for (int s = 0; s < 4; ++s)
      sc[c] = __builtin_amdgcn_mfma_f32_32x32x16_bf16(kf[c * 4 + s], qf[s], sc[c], 0, 0, 0);
  __builtin_amdgcn_s_setprio(0);
#pragma unroll
  for (int c = 0; c < 2; ++c)
#pragma unroll
    for (int r = 0; r < 16; ++r)
      sc[c][r] = __builtin_amdgcn_exp2f(sc[c][r]);
  if (MASK) {
#pragma unroll
    for (int c = 0; c < 2; ++c)
#pragma unroll
      for (int r = 0; r < 16; ++r) {
        int kk = it * 64 + c * 32 + (r & 3) + 8 * (r >> 2) + 4 * h2;
        if (kk >= NTOK) sc[c][r] = 0.f;
      }
  }
  float rs = 0.f;
#pragma unroll
  for (int c = 0; c < 2; ++c)
#pragma unroll
    for (int r = 0; r < 16; ++r) rs += sc[c][r];
  l += rs;
  bf16x8 frag[4];
#pragma unroll
  for (int c = 0; c < 2; ++c) {
    u32 k0 = cvtpk(sc[c][0], sc[c][1]),   k1 = cvtpk(sc[c][2], sc[c][3]);
    u32 k2 = cvtpk(sc[c][4], sc[c][5]),   k3 = cvtpk(sc[c][6], sc[c][7]);
    u32 k4 = cvtpk(sc[c][8], sc[c][9]),   k5 = cvtpk(sc[c][10], sc[c][11]);
    u32 k6 = cvtpk(sc[c][12], sc[c][13]), k7 = cvtpk(sc[c][14], sc[c][15]);
    asm("v_permlane32_swap_b32 %0, %1" : "+v"(k0), "+v"(k2));
    asm("v_permlane32_swap_b32 %0, %1" : "+v"(k1), "+v"(k3));
    asm("v_permlane32_swap_b32 %0, %1" : "+v"(k4), "+v"(k6));
    asm("v_permlane32_swap_b32 %0, %1" : "+v"(k5), "+v"(k7));
    union { u32 u[4]; bf16x8 v; } u0, u1;
    u0.u[0] = k0; u0.u[1] = k1; u0.u[2] = k2; u0.u[3] = k3;
    u1.u[0] = k4; u1.u[1] = k5; u1.u[2] = k6; u1.u[3] = k7;
    frag[c * 2] = u0.v; frag[c * 2 + 1] = u1.v;
  }
  __builtin_amdgcn_s_setprio(1);
#pragma unroll
  for (int hf = 0; hf < 2; ++hf)
#pragma unroll
    for (int s = 0; s < 4; ++s)
      acc[hf] = __builtin_amdgcn_mfma_f32_32x32x16_bf16(vf[hf * 4 + s], frag[s], acc[hf], 0, 0, 0);
  __builtin_amdgcn_s_setprio(0);
}

// ---------------- K3: flash attention — barrier-free, K+V register ping-pong ----------------
__global__ __launch_bounds__(256, 2) void flash_attn(
    const u16* __restrict__ q, const u16* __restrict__ kfr,
    const u16* __restrict__ vfr, u16* __restrict__ y) {
  int f = blockIdx.x;                 // 864 = 8 XCD-chunks * 108
  int xcd = f & 7, idx = f >> 3;
  int bh = xcd * 12 + idx / 9;
  int qt = idx - (idx / 9) * 9;
  int b = bh / 12, h = bh - b * 12;
  int t = threadIdx.x, lane = t & 63, w = t >> 6;
  int lq = lane & 31, h2 = lane >> 5;
  int q0 = qt * 128 + w * 32;
  if (q0 >= NTOK) return;
  int qrow = q0 + lq; if (qrow > NTOK - 1) qrow = NTOK - 1;

  const u16* qp = q + ((size_t)(h * MPAD) + (size_t)b * NTOK + qrow) * 64;
  bf16x8 qf[4];
#pragma unroll
  for (int s = 0; s < 4; ++s)
    qf[s] = *(const bf16x8*)&qp[s * 16 + h2 * 8];

  const u16* kfb = kfr + (size_t)(h * 8 + b) * 34 * 2048 + lane * 8;
  const u16* vfb = vfr + (size_t)(h * 8 + b) * 17 * 4096 + lane * 8;

  f32x16 acc[2] = {};
  float l = 0.f;

  bf16x8 ka[8], kb2[8], va[8], vb[8];
#pragma unroll
  for (int c = 0; c < 2; ++c)
#pragma unroll
    for (int s = 0; s < 4; ++s)
      ka[c * 4 + s] = *(const bf16x8*)(kfb + c * 2048 + s * 512);
#pragma unroll
  for (int hf = 0; hf < 2; ++hf)
#pragma unroll
    for (int s = 0; s < 4; ++s)
      va[hf * 4 + s] = *(const bf16x8*)(vfb + (s * 2 + hf) * 512);

#pragma unroll 1
  for (int i2 = 0; i2 < 8; ++i2) {
    flash_iter<true, false>(ka, kb2, va, vb, 2 * i2 + 1, 2 * i2, kfb, vfb, h2, qf, acc, l);
    flash_iter<true, false>(kb2, ka, vb, va, 2 * i2 + 2, 2 * i2 + 1, kfb, vfb, h2, qf, acc, l);
  }
  flash_iter<false, true>(ka, kb2, va, vb, 0, 16, kfb, vfb, h2, qf, acc, l);

  int row = q0 + lq;
  if (row < NTOK) {
    float lt = l + __shfl_xor(l, 32, 64);
    float inv = 1.f / lt;
    u16* yr = y + ((size_t)(b * NTOK + row)) * CDIM + h * 64;
#pragma unroll
    for (int hf = 0; hf < 2; ++hf)
#pragma unroll
      for (int g = 0; g < 4; ++g) {
        int d0 = hf * 32 + 8 * g + 4 * h2;
        ushort4 o;
        o.x = f2bf(acc[hf][g * 4 + 0] * inv);
        o.y = f2bf(acc[hf][g * 4 + 1] * inv);
        o.z = f2bf(acc[hf][g * 4 + 2] * inv);
        o.w = f2bf(acc[hf][g * 4 + 3] * inv);
        *(ushort4*)&yr[d0] = o;
      }
  }
}

// ---------------- K4: LayerNorm (bf16 in) -> yf fragment layout ----------------
__global__ __launch_bounds__(256) void lnorm(const u16* __restrict__ y,
                                             const float* __restrict__ gamma,
                                             const float* __restrict__ beta,
                                             u16* __restrict__ yf) {
  int row = blockIdx.x;
  const u16* yr = y + (size_t)row * CDIM;
  int t = threadIdx.x;
  float v[3];
  float s = 0.f, s2 = 0.f;
#pragma unroll
  for (int i = 0; i < 3; ++i) {
    v[i] = bf2f(yr[t + 256 * i]);
    s += v[i]; s2 += v[i] * v[i];
  }
#pragma unroll
  for (int msk = 1; msk < 64; msk <<= 1) {
    s  += __shfl_xor(s, msk, 64);
    s2 += __shfl_xor(s2, msk, 64);
  }
  __shared__ float ws[8];
  int w = t >> 6, lane = t & 63;
  if (lane == 0) { ws[w] = s; ws[4 + w] = s2; }
  __syncthreads();
  s = ws[0] + ws[1] + ws[2] + ws[3];
  s2 = ws[4] + ws[5] + ws[6] + ws[7];
  float mu = s * (1.f / 768.f);
  float var = s2 * (1.f / 768.f) - mu * mu;
  float rstd = rsqrtf(var + 1e-6f);
  if (t < 96) {
    union { uint4 u4; u16 u[8]; } iv, ov;
    iv.u4 = *(const uint4*)&yr[t * 8];
    const float* gp = gamma + t * 8;
    const float* bp = beta + t * 8;
#pragma unroll
    for (int j = 0; j < 8; ++j)
      ov.u[j] = f2bf((bf2f(iv.u[j]) - mu) * rstd * gp[j] + bp[j]);
    int kt = t >> 2, ln2 = (row & 15) + 16 * (t & 3), mt = row >> 4;
    *(uint4*)&yf[(((size_t)mt * 24 + kt) * 64 + ln2) * 8] = ov.u4;
  }
}

// ---------------- K5: proj GEMM (fragment-direct, transposed frags) + bias -> fp32 ----------------
__global__ __launch_bounds__(256, 3) void proj_gemm(
    const u16* __restrict__ yf, const u16* __restrict__ wf,
    const float* __restrict__ bias, float* __restrict__ out) {
  const int NB = 6;
  int tau0 = blockIdx.x;
  int xcd = tau0 & 7, pos = tau0 >> 3;
  int tau = (xcd < 6) ? xcd * 49 + pos : 294 + (xcd - 6) * 48 + pos;
  int bx = tau % NB, by = tau / NB;
  int m0 = by * 128, n0 = bx * 128;
  int t = threadIdx.x;
  int lane = t & 63, wave = t >> 6;
  int ln = lane & 15, hi = lane >> 4;
  int wr = wave >> 1, wc = wave & 1;

  f32x4 acc[4][4] = {};
  fdloop<true>(yf, wf, m0, n0, lane, wr, wc, acc);

#pragma unroll
  for (int ii = 0; ii < 4; ++ii) {
    int m = m0 + wr * 64 + ii * 16 + ln;
    if (m < MTOT) {
      float* dr = out + (size_t)m * CDIM;
#pragma unroll
      for (int jj = 0; jj < 4; ++jj) {
        int c4 = n0 + wc * 64 + jj * 16 + hi * 4;
        float4 bv = *(const float4*)(bias + c4);
        float4 o;
        o.x = acc[jj][ii][0] + bv.x;
        o.y = acc[jj][ii][1] + bv.y;
        o.z = acc[jj][ii][2] + bv.z;
        o.w = acc[jj][ii][3] + bv.w;
        *(float4*)(dr + c4) = o;
      }
    }
  }
}

extern "C" void kernel_launch(void* const* d_in, const int* in_sizes, int n_in,
                              void* d_out, int out_size, void* d_ws, size_t ws_size,
                              hipStream_t stream) {
  const float* x      = (const float*)d_in[0];
  const float* rope   = (const float*)d_in[1];
  const float* w_qkv  = (const float*)d_in[2];
  const float* q_bias = (const float*)d_in[3];
  const float* v_bias = (const float*)d_in[4];
  const float* gamma  = (const float*)d_in[5];
  const float* beta   = (const float*)d_in[6];
  const float* w_proj = (const float*)d_in[7];
  const float* b_proj = (const float*)d_in[8];
  float* out = (float*)d_out;

  // Workspace (57.4 MB):
  //  A [0, 12.98M):        xf [528][24][64][8]  -> ybf [8200][768]
  //  B [12.98M, 16.52M):   wfq [144][24][64][8]
  //  C [16.52M, 17.69M):   wfp [48][24][64][8]
  //  D [17.69M, 30.67M):   qbuf [12][8448][64]  -> yf (lnorm frag out)
  //  E [30.67M, 44.04M):   kfr [96][34][4][64][8]
  //  F [44.04M, 57.41M):   vfr [96][17][4][2][64][8]
  char* ws = (char*)d_ws;
  u16* xf   = (u16*)(ws);
  u16* ybf  = (u16*)(ws);
  u16* wfq  = (u16*)(ws + 12976128);
  u16* wfp  = (u16*)(ws + 16515072);
  u16* qbuf = (u16*)(ws + 17694720);
  u16* yf   = (u16*)(ws + 17694720);
  u16* kfr  = (u16*)(ws + 30670848);
  u16* vfr  = (u16*)(ws + 44040192);

  conv_xf<<<dim3(513), 256, 0, stream>>>((const float4*)x, xf);
  transp_wf<<<dim3(144, 24), 64, 0, stream>>>(w_qkv, 2304, wfq);
  transp_wf<<<dim3(48, 24), 64, 0, stream>>>(w_proj, 768, wfp);

  qkv_gemm_all<<<dim3(1170), 256, 0, stream>>>(xf, wfq, q_bias, v_bias, rope,
                                               qbuf, kfr, vfr);
  flash_attn<<<dim3(864), 256, 0, stream>>>(qbuf, kfr, vfr, ybf);
  lnorm<<<8200, 256, 0, stream>>>(ybf, gamma, beta, yf);
  proj_gemm<<<dim3(390), 256, 0, stream>>>(yf, wfp, b_proj, out);
}